// Round 7
// baseline (9717.873 us; speedup 1.0000x reference)
//
#include <hip/hip_runtime.h>
#include <stdint.h>

typedef unsigned short u16;
typedef short short8 __attribute__((ext_vector_type(8)));
typedef float f32x4 __attribute__((ext_vector_type(4)));
typedef int i32x4 __attribute__((ext_vector_type(4)));
typedef unsigned long long u64;

#define NT 512
#define NH 1024
#define G4H 4096
#define HS_ELEMS 33554432ull   // 64*512*1024

static __device__ __forceinline__ u16 f2bf(float f){
  union { float f; unsigned u; } v; v.f = f;
  unsigned r = v.u + 0x7fffu + ((v.u >> 16) & 1u);   // RNE
  return (u16)(r >> 16);
}
static __device__ __forceinline__ float bf2f(u16 s){
  union { unsigned u; float f; } v; v.u = ((unsigned)s) << 16;
  return v.f;
}

// ---------------- fp32 -> bf16 bulk convert ----------------
__global__ void cvt_kernel(const float* __restrict__ in, u16* __restrict__ out, int n8){
  int i = blockIdx.x*blockDim.x + threadIdx.x;
  int stride = gridDim.x*blockDim.x;
  for (; i < n8; i += stride){
    const float4* p = (const float4*)in;
    float4 a = p[2*i], b = p[2*i+1];
    short8 o;
    o[0]=(short)f2bf(a.x); o[1]=(short)f2bf(a.y); o[2]=(short)f2bf(a.z); o[3]=(short)f2bf(a.w);
    o[4]=(short)f2bf(b.x); o[5]=(short)f2bf(b.y); o[6]=(short)f2bf(b.z); o[7]=(short)f2bf(b.w);
    ((short8*)out)[i] = o;
  }
}

// ---------------- init h ring buffer + counters ----------------
__global__ void init_kernel(unsigned* __restrict__ hx, int* __restrict__ cnt){
  int i = blockIdx.x*blockDim.x + threadIdx.x;
  int stride = gridDim.x*blockDim.x;
  for (int k = i; k < 131072; k += stride) hx[k] = 0u;   // 512 KiB of bf16 zeros
  if (i < 256) cnt[i] = 0;
}

// ---------------- phase 1: xg = x @ w_ih^T + b  (bf16 MFMA, m97-style) ----------------
__global__ __launch_bounds__(256) void gemm_xg(
    const u16* __restrict__ A,     // x bf16 [32768][1024]
    const u16* __restrict__ Bw,    // w_ih bf16 [4096][1024]  (B^T layout)
    const float* __restrict__ bias,
    u16* __restrict__ C)           // xg bf16 [32768][4096]
{
  __shared__ u16 lA[128*64];
  __shared__ u16 lB[128*64];
  const int tid = threadIdx.x, lane = tid & 63, w = tid >> 6;
  int bid = blockIdx.x;
  int swz = (bid & 7)*1024 + (bid >> 3);     // XCD swizzle (8192 % 8 == 0, bijective)
  const int brow = swz >> 5;                 // 0..255
  const int bcol = swz & 31;                 // 0..31
  const int wr = (w >> 1)*64, wc = (w & 1)*64;
  f32x4 acc[4][4] = {};

  const int rA0 = brow*128 + w*32;
  const int rB0 = bcol*128 + w*32;
  for (int kt = 0; kt < 1024; kt += 64){
    const u16* gA = A  + (size_t)(rA0 + (lane>>3))*1024 + kt + (lane&7)*8;
    const u16* gB = Bw + (size_t)(rB0 + (lane>>3))*1024 + kt + (lane&7)*8;
#pragma unroll
    for (int c = 0; c < 4; c++){
      __builtin_amdgcn_global_load_lds(
        (const __attribute__((address_space(1))) void*)(gA + (size_t)c*8*1024),
        (__attribute__((address_space(3))) void*)&lA[(w*32 + c*8)*64], 16, 0, 0);
      __builtin_amdgcn_global_load_lds(
        (const __attribute__((address_space(1))) void*)(gB + (size_t)c*8*1024),
        (__attribute__((address_space(3))) void*)&lB[(w*32 + c*8)*64], 16, 0, 0);
    }
    __syncthreads();
#pragma unroll
    for (int kk = 0; kk < 2; kk++){
      short8 fa[4], fb[4];
#pragma unroll
      for (int i = 0; i < 4; i++){
        fa[i] = *(const short8*)&lA[(wr + i*16 + (lane&15))*64 + kk*32 + (lane>>4)*8];
        fb[i] = *(const short8*)&lB[(wc + i*16 + (lane&15))*64 + kk*32 + (lane>>4)*8];
      }
#pragma unroll
      for (int i = 0; i < 4; i++)
#pragma unroll
        for (int jj = 0; jj < 4; jj++)
          acc[i][jj] = __builtin_amdgcn_mfma_f32_16x16x32_bf16(fa[i], fb[jj], acc[i][jj], 0,0,0);
    }
    __syncthreads();
  }
  const int mb = brow*128 + wr + ((lane>>4)<<2);
  const int nb = bcol*128 + wc + (lane&15);
#pragma unroll
  for (int jj = 0; jj < 4; jj++){
    const int n = nb + jj*16;
    const float bv = bias[n];
#pragma unroll
    for (int i = 0; i < 4; i++){
#pragma unroll
      for (int reg = 0; reg < 4; reg++){
        int m = mb + i*16 + reg;
        C[(size_t)m*G4H + n] = f2bf(acc[i][jj][reg] + bv);
      }
    }
  }
}

// ---------------- phase 2: persistent recurrence ----------------
// Grid 256 = 4 batch-groups (16 rows) x 64 col-slice WGs (16 h-cols each).
// Compute path = R1/R6-proven: builtin MFMA on plain VGPR operands.
// Weight residency (R6 witness showed remat-in-loop, VGPR=116): loads emitted
// as asm volatile global_load_dwordx4 — RA cannot rematerialize an asm result,
// so the 128 weight VGPRs stay live for all 512 steps (budget 512 @ 1 wave/EU).
// Explicit vmcnt(0) + sched_barrier(0) fence the opaque loads (rule #18).
// Sync = R6-proven: writer stores -> __syncthreads -> tid0 RELEASE fetch_add;
// reader tid0 relaxed poll (s_sleep) -> barrier -> ACQUIRE fence -> float4
// stage -> LDS. Ring depth 4; cnt>=64t gating bounds skew <= 1 step.
// hs/cs nontemporal: keeps L2 clean so the per-step release wbl2 is ~free.
__global__ __launch_bounds__(256, 1) void lstm_rec(
    const u16* __restrict__ whh,   // [4096][1024] bf16
    const u16* __restrict__ xg,    // [64*512][4096] bf16 (row b*512+t), bias included
    u16* __restrict__ hx,          // [4][4][32][64][8] bf16 (fragment order)
    int* cnt,                      // [4*64] (256B-spaced per group)
    float* __restrict__ hs,
    float* __restrict__ cs)
{
  __shared__ u16 lds_h[16384];     // 32 KiB: group h in fragment order [32][64][8]
  const int tid  = threadIdx.x;
  const int lane = tid & 63;
  const int w    = tid >> 6;
  const int bid  = blockIdx.x;
  const int g    = bid >> 6;          // batch group 0..3
  const int j    = bid & 63;          // col-slice 0..63
  const int q    = (lane & 15) >> 2;  // gate type 0:i 1:f 2:g 3:o
  const int col  = j*16 + w*4 + (lane & 3);   // h column 0..1023
  const int Gr   = q*1024 + col;              // gate row 0..4095
  const int mloc = (lane >> 4) * 4;           // batch-in-group base

  // ---- weights -> VGPRs via OPAQUE asm loads (not rematerializable) ----
  i32x4 wq[32];
  {
    const u16* wbase = whh + (size_t)Gr*1024 + ((lane>>4)*8);
#pragma unroll
    for (int kk = 0; kk < 32; kk++){
      const u16* a = wbase + kk*32;    // kk*64 bytes
      asm volatile("global_load_dwordx4 %0, %1, off"
                   : "=v"(wq[kk]) : "v"(a));
    }
    asm volatile("s_waitcnt vmcnt(0)" ::: "memory");
    __builtin_amdgcn_sched_barrier(0);
  }

  float c_st[4] = {0.f,0.f,0.f,0.f};
  int* cntg = cnt + g*64;

  for (int t = 0; t < NT; t++){
    // xg prefetch (independent of h) — hides HBM latency under the poll
    float xv[4];
#pragma unroll
    for (int reg = 0; reg < 4; reg++){
      int b = g*16 + mloc + reg;
      xv[reg] = bf2f(xg[((size_t)b*NT + t)*G4H + Gr]);
    }
    // ---- wait for h(t-1): leader poll -> barrier -> acquire fence ----
    if (t > 0){
      if (tid == 0){
        const int need = t * 64;
        while (__hip_atomic_load(cntg, __ATOMIC_RELAXED, __HIP_MEMORY_SCOPE_AGENT) < need)
          __builtin_amdgcn_s_sleep(2);
      }
      __syncthreads();
      __builtin_amdgcn_fence(__ATOMIC_ACQUIRE, "agent");   // buffer_inv
    }
    // ---- stage h(t-1) -> LDS (plain coalesced float4 loads, 32 KiB/WG) ----
    const float4* hb = (const float4*)(hx + ((size_t)(((t+3)&3)*4 + g)) * 16384);
#pragma unroll
    for (int k = 0; k < 8; k++){
      ((float4*)lds_h)[tid + 256*k] = hb[tid + 256*k];
    }
    __syncthreads();

    // ---- gates = xg + h @ w_hh^T : 32 builtin MFMAs, weights from VGPRs ----
    f32x4 accv[4];
    accv[0] = (f32x4){xv[0], xv[1], xv[2], xv[3]};
    accv[1] = (f32x4){0.f,0.f,0.f,0.f};
    accv[2] = accv[1]; accv[3] = accv[1];
#pragma unroll
    for (int kk = 0; kk < 32; kk++){
      short8 av = *(const short8*)&lds_h[(kk*64 + lane)*8];
      short8 bv = __builtin_bit_cast(short8, wq[kk]);
      accv[kk & 3] = __builtin_amdgcn_mfma_f32_16x16x32_bf16(av, bv, accv[kk & 3], 0,0,0);
    }
    f32x4 gv = (accv[0] + accv[1]) + (accv[2] + accv[3]);

    // ---- activations + outputs + h publish ----
    u16* wbuf = hx + ((size_t)((t&3)*4 + g)) * 16384;
#pragma unroll
    for (int reg = 0; reg < 4; reg++){
      float xg_ = gv[reg];
      float sig = 1.f / (1.f + __expf(-xg_));
      float th  = 1.f - 2.f / (1.f + __expf(2.f*xg_));
      float a   = (q == 2) ? th : sig;
      float v4  = __shfl_xor(a, 4);
      float v8  = __shfl_xor(a, 8);
      float v12 = __shfl_xor(a, 12);
      float iv  = (q==0)?a :(q==1)?v4:(q==2)?v8:v12;
      float fv  = (q==1)?a :(q==0)?v4:(q==3)?v8:v12;
      float gg  = (q==2)?a :(q==3)?v4:(q==0)?v8:v12;
      float ov  = (q==3)?a :(q==2)?v4:(q==1)?v8:v12;
      float cn  = fv*c_st[reg] + iv*gg;
      c_st[reg] = cn;
      float tc  = 1.f - 2.f / (1.f + __expf(2.f*cn));
      float hn  = ov * tc;
      int b = g*16 + mloc + reg;
      size_t oidx = ((size_t)b*NT + t)*NH + col;
      if (q == 1) __builtin_nontemporal_store(hn, &hs[oidx]);
      if (q == 2) __builtin_nontemporal_store(cn, &cs[oidx]);
      if (q == 0){
        // publish h in fragment order: elem (m, col) -> [col>>5][((col&31)>>3)*16+m][col&7]
        int sub = ((col & 31) >> 3)*16 + (mloc + reg);
        wbuf[(size_t)((col >> 5)*64 + sub)*8 + (col & 7)] = f2bf(hn);
      }
    }
    __syncthreads();   // all waves' publish stores drained (vmcnt0 before barrier)
    if (tid == 0)
      __hip_atomic_fetch_add(cntg, 1, __ATOMIC_RELEASE, __HIP_MEMORY_SCOPE_AGENT);
  }
}

extern "C" void kernel_launch(void* const* d_in, const int* in_sizes, int n_in,
                              void* d_out, int out_size, void* d_ws, size_t ws_size,
                              hipStream_t stream){
  const float* x    = (const float*)d_in[0];
  const float* wih  = (const float*)d_in[1];
  const float* whh  = (const float*)d_in[2];
  const float* bias = (const float*)d_in[3];
  float* hs = (float*)d_out;
  float* cs = hs + HS_ELEMS;
  char* ws = (char*)d_ws;
  // ws layout (~337 MiB)
  u16* xg   = (u16*)(ws + 0);              // 256 MiB
  u16* xb   = (u16*)(ws + 268435456ull);   // 64 MiB
  u16* wihb = (u16*)(ws + 335544320ull);   // 8 MiB
  u16* whhb = (u16*)(ws + 343932928ull);   // 8 MiB
  u16* hx   = (u16*)(ws + 352321536ull);   // 512 KiB
  int* cnt  = (int*)(ws + 352845824ull);   // 1 KiB

  cvt_kernel<<<2048, 256, 0, stream>>>(x,   xb,   33554432/8);
  cvt_kernel<<<512,  256, 0, stream>>>(wih, wihb, 4194304/8);
  cvt_kernel<<<512,  256, 0, stream>>>(whh, whhb, 4194304/8);
  init_kernel<<<64,  256, 0, stream>>>((unsigned*)hx, cnt);
  gemm_xg<<<8192, 256, 0, stream>>>(xb, wihb, bias, xg);

  const u16* whhb_c = whhb; const u16* xg_c = xg;
  u16* hx_p = hx; int* cnt_p = cnt; float* hs_p = hs; float* cs_p = cs;
  void* args[6];
  args[0] = (void*)&whhb_c;
  args[1] = (void*)&xg_c;
  args[2] = (void*)&hx_p;
  args[3] = (void*)&cnt_p;
  args[4] = (void*)&hs_p;
  args[5] = (void*)&cs_p;
  hipLaunchCooperativeKernel((const void*)lstm_rec, dim3(256), dim3(256), args, 0, stream);
}

// Round 8
// 4015.253 us; speedup vs baseline: 2.4202x; 2.4202x over previous
//
#include <hip/hip_runtime.h>
#include <stdint.h>

typedef unsigned short u16;
typedef short short8 __attribute__((ext_vector_type(8)));
typedef float f32x4 __attribute__((ext_vector_type(4)));
typedef int i32x4 __attribute__((ext_vector_type(4)));
typedef unsigned long long u64;

#define NT 512
#define NH 1024
#define G4H 4096
#define HS_ELEMS 33554432ull   // 64*512*1024

static __device__ __forceinline__ u16 f2bf(float f){
  union { float f; unsigned u; } v; v.f = f;
  unsigned r = v.u + 0x7fffu + ((v.u >> 16) & 1u);   // RNE
  return (u16)(r >> 16);
}
static __device__ __forceinline__ float bf2f(u16 s){
  union { unsigned u; float f; } v; v.u = ((unsigned)s) << 16;
  return v.f;
}

// ---------------- fp32 -> bf16 bulk convert ----------------
__global__ void cvt_kernel(const float* __restrict__ in, u16* __restrict__ out, int n8){
  int i = blockIdx.x*blockDim.x + threadIdx.x;
  int stride = gridDim.x*blockDim.x;
  for (; i < n8; i += stride){
    const float4* p = (const float4*)in;
    float4 a = p[2*i], b = p[2*i+1];
    short8 o;
    o[0]=(short)f2bf(a.x); o[1]=(short)f2bf(a.y); o[2]=(short)f2bf(a.z); o[3]=(short)f2bf(a.w);
    o[4]=(short)f2bf(b.x); o[5]=(short)f2bf(b.y); o[6]=(short)f2bf(b.z); o[7]=(short)f2bf(b.w);
    ((short8*)out)[i] = o;
  }
}

// ---------------- init h ring buffer + counters ----------------
__global__ void init_kernel(unsigned* __restrict__ hx, int* __restrict__ cnt){
  int i = blockIdx.x*blockDim.x + threadIdx.x;
  int stride = gridDim.x*blockDim.x;
  for (int k = i; k < 131072; k += stride) hx[k] = 0u;   // 512 KiB of bf16 zeros
  if (i < 256) cnt[i] = 0;
}

// ---------------- phase 1: xg = x @ w_ih^T + b  (bf16 MFMA, m97-style) ----------------
__global__ __launch_bounds__(256) void gemm_xg(
    const u16* __restrict__ A,     // x bf16 [32768][1024]
    const u16* __restrict__ Bw,    // w_ih bf16 [4096][1024]  (B^T layout)
    const float* __restrict__ bias,
    u16* __restrict__ C)           // xg bf16 [32768][4096]
{
  __shared__ u16 lA[128*64];
  __shared__ u16 lB[128*64];
  const int tid = threadIdx.x, lane = tid & 63, w = tid >> 6;
  int bid = blockIdx.x;
  int swz = (bid & 7)*1024 + (bid >> 3);     // XCD swizzle (8192 % 8 == 0, bijective)
  const int brow = swz >> 5;                 // 0..255
  const int bcol = swz & 31;                 // 0..31
  const int wr = (w >> 1)*64, wc = (w & 1)*64;
  f32x4 acc[4][4] = {};

  const int rA0 = brow*128 + w*32;
  const int rB0 = bcol*128 + w*32;
  for (int kt = 0; kt < 1024; kt += 64){
    const u16* gA = A  + (size_t)(rA0 + (lane>>3))*1024 + kt + (lane&7)*8;
    const u16* gB = Bw + (size_t)(rB0 + (lane>>3))*1024 + kt + (lane&7)*8;
#pragma unroll
    for (int c = 0; c < 4; c++){
      __builtin_amdgcn_global_load_lds(
        (const __attribute__((address_space(1))) void*)(gA + (size_t)c*8*1024),
        (__attribute__((address_space(3))) void*)&lA[(w*32 + c*8)*64], 16, 0, 0);
      __builtin_amdgcn_global_load_lds(
        (const __attribute__((address_space(1))) void*)(gB + (size_t)c*8*1024),
        (__attribute__((address_space(3))) void*)&lB[(w*32 + c*8)*64], 16, 0, 0);
    }
    __syncthreads();
#pragma unroll
    for (int kk = 0; kk < 2; kk++){
      short8 fa[4], fb[4];
#pragma unroll
      for (int i = 0; i < 4; i++){
        fa[i] = *(const short8*)&lA[(wr + i*16 + (lane&15))*64 + kk*32 + (lane>>4)*8];
        fb[i] = *(const short8*)&lB[(wc + i*16 + (lane&15))*64 + kk*32 + (lane>>4)*8];
      }
#pragma unroll
      for (int i = 0; i < 4; i++)
#pragma unroll
        for (int jj = 0; jj < 4; jj++)
          acc[i][jj] = __builtin_amdgcn_mfma_f32_16x16x32_bf16(fa[i], fb[jj], acc[i][jj], 0,0,0);
    }
    __syncthreads();
  }
  const int mb = brow*128 + wr + ((lane>>4)<<2);
  const int nb = bcol*128 + wc + (lane&15);
#pragma unroll
  for (int jj = 0; jj < 4; jj++){
    const int n = nb + jj*16;
    const float bv = bias[n];
#pragma unroll
    for (int i = 0; i < 4; i++){
#pragma unroll
      for (int reg = 0; reg < 4; reg++){
        int m = mb + i*16 + reg;
        C[(size_t)m*G4H + n] = f2bf(acc[i][jj][reg] + bv);
      }
    }
  }
}

// ---------------- phase 2: persistent recurrence (FENCE-FREE protocol) ----------------
// Grid 256 = 4 batch-groups (16 rows) x 64 col-slice WGs (16 h-cols each).
// Compute core = R6/R7-proven (plain weight loads + builtin MFMA; compiler
// allocates weights to AGPRs itself — verified: no per-step whh refetch).
// Protocol experiment (R2's design, now unconfounded from the AGPR bug):
//   writer: paired u32 RELAXED AGENT atomic stores (sc1 write-through to
//           coherence point) -> __syncthreads (per-wave vmcnt(0) = stores
//           acked) -> tid0 RELAXED fetch_add (RMW at coherence point).
//   reader: tid0 relaxed poll (s_sleep) -> barrier -> stage h via RELAXED
//           AGENT atomic u64 loads (sc1, bypass stale L2) -> LDS.
// ZERO buffer_wbl2 / buffer_inv — the hypothesized 17.7us/step cost.
// Ring depth 4; cnt>=64t gating bounds skew <= 1 step => race-free.
__global__ __launch_bounds__(256, 1) void lstm_rec(
    const u16* __restrict__ whh,   // [4096][1024] bf16
    const u16* __restrict__ xg,    // [64*512][4096] bf16 (row b*512+t), bias included
    u16* __restrict__ hx,          // [4][4][32][64][8] bf16 (fragment order)
    int* cnt,                      // [4*64] (256B-spaced per group)
    float* __restrict__ hs,
    float* __restrict__ cs)
{
  __shared__ u16 lds_h[16384];     // 32 KiB: group h in fragment order [32][64][8]
  const int tid  = threadIdx.x;
  const int lane = tid & 63;
  const int w    = tid >> 6;
  const int bid  = blockIdx.x;
  const int g    = bid >> 6;          // batch group 0..3
  const int j    = bid & 63;          // col-slice 0..63
  const int q    = (lane & 15) >> 2;  // gate type 0:i 1:f 2:g 3:o
  const int col  = j*16 + w*4 + (lane & 3);   // h column 0..1023
  const int Gr   = q*1024 + col;              // gate row 0..4095
  const int mloc = (lane >> 4) * 4;           // batch-in-group base

  // ---- weights -> regs (R6-proven; compiler parks them in AGPRs) ----
  i32x4 wq[32];
  {
    const i32x4* wp = (const i32x4*)(whh + (size_t)Gr*1024 + ((lane>>4)*8));
#pragma unroll
    for (int kk = 0; kk < 32; kk++) wq[kk] = wp[kk*4];
#pragma unroll
    for (int kk = 0; kk < 32; kk++) asm volatile("" : "+v"(wq[kk]));
  }

  float c_st[4] = {0.f,0.f,0.f,0.f};
  int* cntg = cnt + g*64;

  for (int t = 0; t < NT; t++){
    // xg prefetch (independent of h) — hides HBM latency under the poll
    float xv[4];
#pragma unroll
    for (int reg = 0; reg < 4; reg++){
      int b = g*16 + mloc + reg;
      xv[reg] = bf2f(xg[((size_t)b*NT + t)*G4H + Gr]);
    }
    // ---- wait for h(t-1): leader relaxed poll -> barrier (NO fence) ----
    if (t > 0){
      if (tid == 0){
        const int need = t * 64;
        while (__hip_atomic_load(cntg, __ATOMIC_RELAXED, __HIP_MEMORY_SCOPE_AGENT) < need)
          __builtin_amdgcn_s_sleep(2);
      }
      __syncthreads();
    }
    // ---- stage h(t-1) -> LDS via sc1 atomic u64 loads (bypass stale L2) ----
    const u64* hb64 = (const u64*)(hx + ((size_t)(((t+3)&3)*4 + g)) * 16384);
#pragma unroll
    for (int k = 0; k < 16; k++){
      int W = tid + 256*k;
      u64 v = __hip_atomic_load(hb64 + W, __ATOMIC_RELAXED, __HIP_MEMORY_SCOPE_AGENT);
      *(u64*)&lds_h[W*4] = v;
    }
    __syncthreads();

    // ---- gates = xg + h @ w_hh^T : 32 builtin MFMAs ----
    f32x4 accv[4];
    accv[0] = (f32x4){xv[0], xv[1], xv[2], xv[3]};
    accv[1] = (f32x4){0.f,0.f,0.f,0.f};
    accv[2] = accv[1]; accv[3] = accv[1];
#pragma unroll
    for (int kk = 0; kk < 32; kk++){
      short8 av = *(const short8*)&lds_h[(kk*64 + lane)*8];
      short8 bv = __builtin_bit_cast(short8, wq[kk]);
      accv[kk & 3] = __builtin_amdgcn_mfma_f32_16x16x32_bf16(av, bv, accv[kk & 3], 0,0,0);
    }
    f32x4 gv = (accv[0] + accv[1]) + (accv[2] + accv[3]);

    // ---- activations + outputs + h publish ----
    u16* wbuf = hx + ((size_t)((t&3)*4 + g)) * 16384;
#pragma unroll
    for (int reg = 0; reg < 4; reg++){
      float xg_ = gv[reg];
      float sig = 1.f / (1.f + __expf(-xg_));
      float th  = 1.f - 2.f / (1.f + __expf(2.f*xg_));
      float a   = (q == 2) ? th : sig;
      float v4  = __shfl_xor(a, 4);
      float v8  = __shfl_xor(a, 8);
      float v12 = __shfl_xor(a, 12);
      float iv  = (q==0)?a :(q==1)?v4:(q==2)?v8:v12;
      float fv  = (q==1)?a :(q==0)?v4:(q==3)?v8:v12;
      float gg  = (q==2)?a :(q==3)?v4:(q==0)?v8:v12;
      float ov  = (q==3)?a :(q==2)?v4:(q==1)?v8:v12;
      float cn  = fv*c_st[reg] + iv*gg;
      c_st[reg] = cn;
      float tc  = 1.f - 2.f / (1.f + __expf(2.f*cn));
      float hn  = ov * tc;
      int b = g*16 + mloc + reg;
      size_t oidx = ((size_t)b*NT + t)*NH + col;
      if (q == 1) __builtin_nontemporal_store(hn, &hs[oidx]);
      if (q == 2) __builtin_nontemporal_store(cn, &cs[oidx]);
      // publish h via paired u32 sc1 atomic store (write-through to L3)
      float hp = __shfl_xor(hn, 1);          // partner column's h
      if (q == 0 && (lane & 1) == 0){
        unsigned word = (unsigned)f2bf(hn) | ((unsigned)f2bf(hp) << 16);
        int sub = ((col & 31) >> 3)*16 + (mloc + reg);
        int idx16 = ((col >> 5)*64 + sub)*8 + (col & 7);   // even
        __hip_atomic_store((unsigned*)(wbuf + idx16), word,
                           __ATOMIC_RELAXED, __HIP_MEMORY_SCOPE_AGENT);
      }
    }
    __syncthreads();   // per-wave vmcnt(0): all publish stores ACKED at L3
    if (tid == 0)
      __hip_atomic_fetch_add(cntg, 1, __ATOMIC_RELAXED, __HIP_MEMORY_SCOPE_AGENT);
  }
}

extern "C" void kernel_launch(void* const* d_in, const int* in_sizes, int n_in,
                              void* d_out, int out_size, void* d_ws, size_t ws_size,
                              hipStream_t stream){
  const float* x    = (const float*)d_in[0];
  const float* wih  = (const float*)d_in[1];
  const float* whh  = (const float*)d_in[2];
  const float* bias = (const float*)d_in[3];
  float* hs = (float*)d_out;
  float* cs = hs + HS_ELEMS;
  char* ws = (char*)d_ws;
  // ws layout (~337 MiB)
  u16* xg   = (u16*)(ws + 0);              // 256 MiB
  u16* xb   = (u16*)(ws + 268435456ull);   // 64 MiB
  u16* wihb = (u16*)(ws + 335544320ull);   // 8 MiB
  u16* whhb = (u16*)(ws + 343932928ull);   // 8 MiB
  u16* hx   = (u16*)(ws + 352321536ull);   // 512 KiB
  int* cnt  = (int*)(ws + 352845824ull);   // 1 KiB

  cvt_kernel<<<2048, 256, 0, stream>>>(x,   xb,   33554432/8);
  cvt_kernel<<<512,  256, 0, stream>>>(wih, wihb, 4194304/8);
  cvt_kernel<<<512,  256, 0, stream>>>(whh, whhb, 4194304/8);
  init_kernel<<<64,  256, 0, stream>>>((unsigned*)hx, cnt);
  gemm_xg<<<8192, 256, 0, stream>>>(xb, wihb, bias, xg);

  const u16* whhb_c = whhb; const u16* xg_c = xg;
  u16* hx_p = hx; int* cnt_p = cnt; float* hs_p = hs; float* cs_p = cs;
  void* args[6];
  args[0] = (void*)&whhb_c;
  args[1] = (void*)&xg_c;
  args[2] = (void*)&hx_p;
  args[3] = (void*)&cnt_p;
  args[4] = (void*)&hs_p;
  args[5] = (void*)&cs_p;
  hipLaunchCooperativeKernel((const void*)lstm_rec, dim3(256), dim3(256), args, 0, stream);
}